// Round 1
// baseline (678.121 us; speedup 1.0000x reference)
//
#include <hip/hip_runtime.h>
#include <hip/hip_bf16.h>
#include <stdint.h>

#define BB   8
#define CCH  128
#define HH   256
#define WWD  256
#define OCC  64
#define HWW  (HH*WWD)

typedef __attribute__((ext_vector_type(8))) short  bf16x8;
typedef __attribute__((ext_vector_type(4))) float  f32x4;
typedef __attribute__((ext_vector_type(4))) unsigned int u32x4;
typedef __attribute__((ext_vector_type(2))) float  f32x2;

static __device__ __forceinline__ unsigned cvt_pk_bf16(float lo, float hi) {
    unsigned r;
    asm("v_cvt_pk_bf16_f32 %0, %1, %2" : "=v"(r) : "v"(lo), "v"(hi));
    return r;
}
static __device__ __forceinline__ float bf16lo_to_f(unsigned u) {
    union { unsigned u; float f; } c; c.u = u << 16; return c.f;
}
static __device__ __forceinline__ float bf16hi_to_f(unsigned u) {
    union { unsigned u; float f; } c; c.u = u & 0xffff0000u; return c.f;
}

// Repack Wc (OC, Q*C, 3, 3) fp32 -> Wb[tap][q][oc][c] bf16
__global__ void prep_w(const float* __restrict__ Wc, unsigned short* __restrict__ Wb) {
    int t = blockIdx.x * 256 + threadIdx.x;       // t == destination index
    int c   = t & 127;
    int oc  = (t >> 7) & 63;
    int qt  = t >> 13;                            // tap*3 + q, 0..26
    int q   = qt % 3;
    int tap = qt / 3;
    float v = Wc[(size_t)(oc * 384 + q * 128 + c) * 9 + tap];
    Wb[t] = (unsigned short)(cvt_pk_bf16(v, v) & 0xffffu);
}

// Per-pixel LayerNorm over C=128, write xn as bf16 in (B,H,W,C)
__global__ __launch_bounds__(256) void ln_kernel(
        const float* __restrict__ x, const float* __restrict__ gamma,
        const float* __restrict__ beta, unsigned short* __restrict__ xn) {
    int p  = blockIdx.x * 256 + threadIdx.x;      // global pixel
    int b  = p >> 16;
    int hw = p & 65535;
    const float* xb = x + (size_t)b * CCH * HWW + hw;
    unsigned buf[64];
    float sum = 0.f, sumsq = 0.f;
    #pragma unroll
    for (int cp = 0; cp < 64; ++cp) {
        float v0 = xb[(size_t)(2 * cp) * HWW];
        float v1 = xb[(size_t)(2 * cp + 1) * HWW];
        sum   += v0 + v1;
        sumsq += v0 * v0 + v1 * v1;
        buf[cp] = cvt_pk_bf16(v0, v1);
    }
    float mu  = sum * (1.f / 128.f);
    float var = sumsq * (1.f / 128.f) - mu * mu;
    float rs  = rsqrtf(var + 1e-5f);
    unsigned short* outp = xn + (size_t)p * 128;
    #pragma unroll
    for (int g = 0; g < 16; ++g) {
        u32x4 o;
        #pragma unroll
        for (int k = 0; k < 4; ++k) {
            int cp = g * 4 + k;
            float f0 = bf16lo_to_f(buf[cp]);
            float f1 = bf16hi_to_f(buf[cp]);
            int c0 = cp * 2, c1 = cp * 2 + 1;
            float y0 = fmaf((f0 - mu) * rs, gamma[c0], beta[c0]);
            float y1 = fmaf((f1 - mu) * rs, gamma[c1], beta[c1]);
            o[k] = cvt_pk_bf16(y0, y1);
        }
        *(u32x4*)(outp + g * 8) = o;
    }
}

// Implicit-GEMM conv: block = one output row (b,y); 4 waves, each M=64 px, N=64 oc.
// Powers x^2,x^3 computed in-register from bf16 xn. Fused pixel-unshuffle store.
__global__ __launch_bounds__(256, 2) void conv_kernel(
        const unsigned short* __restrict__ xn,
        const unsigned short* __restrict__ Wb,
        float* __restrict__ out) {
    int bid  = blockIdx.x;
    int y    = bid & 255;
    int b    = bid >> 8;
    int lane = threadIdx.x & 63;
    int w    = threadIdx.x >> 6;
    int l15  = lane & 15;
    int l4   = lane >> 4;
    int koff = l4 * 8;

    f32x4 acc[4][4];
    #pragma unroll
    for (int mt = 0; mt < 4; ++mt)
        #pragma unroll
        for (int nt = 0; nt < 4; ++nt)
            acc[mt][nt] = (f32x4){0.f, 0.f, 0.f, 0.f};

    const unsigned short* xb = xn + (size_t)b * HWW * 128;
    int xbase = w * 64 + l15;

    #pragma unroll 1
    for (int ky = 0; ky < 3; ++ky) {
        int yy = y + ky - 1;
        if ((unsigned)yy >= 256u) continue;
        const unsigned short* xr = xb + (size_t)yy * WWD * 128;
        #pragma unroll
        for (int kx = 0; kx < 3; ++kx) {
            int tap = ky * 3 + kx;
            const unsigned short* wt = Wb + (size_t)tap * 3 * 64 * 128 + l15 * 128 + koff;
            #pragma unroll
            for (int cc = 0; cc < 4; ++cc) {
                int cb = cc * 32 + koff;
                bf16x8 a1[4], a2[4], a3[4];
                #pragma unroll
                for (int mt = 0; mt < 4; ++mt) {
                    int xx = xbase + mt * 16 + kx - 1;
                    bool valid = (unsigned)xx < 256u;
                    const unsigned short* ap = xr + ((size_t)(valid ? xx : 0) * 128 + cb);
                    u32x4 u = *(const u32x4*)ap;
                    if (!valid) u = (u32x4){0u, 0u, 0u, 0u};
                    a1[mt] = __builtin_bit_cast(bf16x8, u);
                    u32x4 u2, u3;
                    #pragma unroll
                    for (int k = 0; k < 4; ++k) {
                        float f0 = bf16lo_to_f(u[k]);
                        float f1 = bf16hi_to_f(u[k]);
                        float g0 = f0 * f0, g1 = f1 * f1;
                        u2[k] = cvt_pk_bf16(g0, g1);
                        u3[k] = cvt_pk_bf16(g0 * f0, g1 * f1);
                    }
                    a2[mt] = __builtin_bit_cast(bf16x8, u2);
                    a3[mt] = __builtin_bit_cast(bf16x8, u3);
                }
                #pragma unroll
                for (int q = 0; q < 3; ++q) {
                    const unsigned short* wq = wt + q * 64 * 128 + cc * 32;
                    #pragma unroll
                    for (int nt = 0; nt < 4; ++nt) {
                        bf16x8 bv = *(const bf16x8*)(wq + nt * 16 * 128);
                        #pragma unroll
                        for (int mt = 0; mt < 4; ++mt) {
                            bf16x8 av = (q == 0) ? a1[mt] : (q == 1) ? a2[mt] : a3[mt];
                            acc[mt][nt] = __builtin_amdgcn_mfma_f32_16x16x32_bf16(
                                av, bv, acc[mt][nt], 0, 0, 0);
                        }
                    }
                }
            }
        }
    }

    // Epilogue: fused PixelUnshuffle(2). y conv output (b, oc, y, x) ->
    // out[b, oc*4 + (y&1)*2 + (x&1), y>>1, x>>1]; pack x2,x2+1 as float2.
    int y2 = y >> 1, s = y & 1;
    #pragma unroll
    for (int mt = 0; mt < 4; ++mt) {
        int X0 = w * 64 + mt * 16 + l4 * 4;   // even
        int x2 = X0 >> 1;
        #pragma unroll
        for (int nt = 0; nt < 4; ++nt) {
            int oc = nt * 16 + l15;
            #pragma unroll
            for (int rr = 0; rr < 2; ++rr) {
                int ch = oc * 4 + s * 2 + rr;
                size_t off = ((size_t)(b * 256 + ch) * 128 + y2) * 128 + x2;
                f32x2 v;
                v.x = acc[mt][nt][rr];
                v.y = acc[mt][nt][rr + 2];
                *(f32x2*)(out + off) = v;
            }
        }
    }
}

extern "C" void kernel_launch(void* const* d_in, const int* in_sizes, int n_in,
                              void* d_out, int out_size, void* d_ws, size_t ws_size,
                              hipStream_t stream) {
    const float* x     = (const float*)d_in[0];
    const float* gamma = (const float*)d_in[1];
    const float* beta  = (const float*)d_in[2];
    const float* Wc    = (const float*)d_in[3];
    float* out = (float*)d_out;

    const size_t xn_bytes = (size_t)BB * HWW * CCH * 2;          // 134217728
    const size_t wb_bytes = (size_t)27 * OCC * CCH * 2;          // 442368
    if (ws_size < xn_bytes + wb_bytes) return;                   // visible failure
    unsigned short* xn = (unsigned short*)d_ws;
    unsigned short* Wb = (unsigned short*)((char*)d_ws + xn_bytes);

    hipLaunchKernelGGL(prep_w, dim3(864), dim3(256), 0, stream, Wc, Wb);
    hipLaunchKernelGGL(ln_kernel, dim3(2048), dim3(256), 0, stream, x, gamma, beta, xn);
    hipLaunchKernelGGL(conv_kernel, dim3(2048), dim3(256), 0, stream, xn, Wb, out);
}

// Round 2
// 445.627 us; speedup vs baseline: 1.5217x; 1.5217x over previous
//
#include <hip/hip_runtime.h>
#include <hip/hip_bf16.h>
#include <stdint.h>

#define BB   8
#define CCH  128
#define HH   256
#define WWD  256
#define OCC  64
#define HWW  (HH*WWD)
#define PLANE (BB*HWW*32)          // elems per 32-ch plane of xn2

typedef __attribute__((ext_vector_type(8))) short  bf16x8;
typedef __attribute__((ext_vector_type(4))) float  f32x4;
typedef __attribute__((ext_vector_type(4))) unsigned int u32x4;
typedef __attribute__((ext_vector_type(2))) float  f32x2;

static __device__ __forceinline__ unsigned cvt_pk_bf16(float lo, float hi) {
    unsigned r;
    asm("v_cvt_pk_bf16_f32 %0, %1, %2" : "=v"(r) : "v"(lo), "v"(hi));
    return r;
}
static __device__ __forceinline__ float bf16lo_to_f(unsigned u) {
    union { unsigned u; float f; } c; c.u = u << 16; return c.f;
}
static __device__ __forceinline__ float bf16hi_to_f(unsigned u) {
    union { unsigned u; float f; } c; c.u = u & 0xffff0000u; return c.f;
}

// Repack Wc (OC, Q*C, 3, 3) fp32 -> Wb2: per-fragment lane-order bf16.
// frag = ((tap*3+q)*4+cc)*4+nt ; within frag: lane*8 contiguous bf16,
// lane -> (oc = nt*16 + (lane&15), k = cc*32 + (lane>>4)*8 + j).
__global__ void prep_w(const float* __restrict__ Wc, unsigned short* __restrict__ Wb2) {
    int task = blockIdx.x * 256 + threadIdx.x;    // 27648 tasks, one bf16x8 each
    int lane = task & 63;
    int frag = task >> 6;
    int nt   = frag & 3;
    int cc   = (frag >> 2) & 3;
    int tq   = frag >> 4;                         // tap*3+q, 0..26
    int q    = tq % 3;
    int tap  = tq / 3;
    int oc   = nt * 16 + (lane & 15);
    int kb   = cc * 32 + (lane >> 4) * 8;
    u32x4 o;
    #pragma unroll
    for (int k = 0; k < 4; ++k) {
        float v0 = Wc[(size_t)(oc * 384 + q * 128 + kb + 2 * k) * 9 + tap];
        float v1 = Wc[(size_t)(oc * 384 + q * 128 + kb + 2 * k + 1) * 9 + tap];
        o[k] = cvt_pk_bf16(v0, v1);
    }
    *(u32x4*)(Wb2 + (size_t)task * 8) = o;
}

// Per-pixel LayerNorm over C=128; write xn2 as 4 planes [cc][b][y][x][32ch] bf16
__global__ __launch_bounds__(256) void ln_kernel(
        const float* __restrict__ x, const float* __restrict__ gamma,
        const float* __restrict__ beta, unsigned short* __restrict__ xn2) {
    int p  = blockIdx.x * 256 + threadIdx.x;      // global pixel
    int b  = p >> 16;
    int hw = p & 65535;
    const float* xb = x + (size_t)b * CCH * HWW + hw;
    unsigned buf[64];
    float sum = 0.f, sumsq = 0.f;
    #pragma unroll
    for (int cp = 0; cp < 64; ++cp) {
        float v0 = xb[(size_t)(2 * cp) * HWW];
        float v1 = xb[(size_t)(2 * cp + 1) * HWW];
        sum   += v0 + v1;
        sumsq += v0 * v0 + v1 * v1;
        buf[cp] = cvt_pk_bf16(v0, v1);
    }
    float mu  = sum * (1.f / 128.f);
    float var = sumsq * (1.f / 128.f) - mu * mu;
    float rs  = rsqrtf(var + 1e-5f);
    size_t pix = (size_t)p * 32;
    #pragma unroll
    for (int g = 0; g < 16; ++g) {
        u32x4 o;
        #pragma unroll
        for (int k = 0; k < 4; ++k) {
            int cp = g * 4 + k;
            float f0 = bf16lo_to_f(buf[cp]);
            float f1 = bf16hi_to_f(buf[cp]);
            int c0 = cp * 2, c1 = cp * 2 + 1;
            float y0 = fmaf((f0 - mu) * rs, gamma[c0], beta[c0]);
            float y1 = fmaf((f1 - mu) * rs, gamma[c1], beta[c1]);
            o[k] = cvt_pk_bf16(y0, y1);
        }
        *(u32x4*)(xn2 + (size_t)(g >> 2) * PLANE + pix + (g & 3) * 8) = o;
    }
}

// Implicit-GEMM conv. Block = 8 rows x 32 px x 64 oc; 4 waves (each 2 rows x 32 px).
// Per 32-ch chunk: stage x^1,x^2,x^3 of 10x34 halo tile in LDS (powers once),
// then 27 taps of MFMA with LDS A-frags and coalesced repacked B-frags.
__global__ __launch_bounds__(256, 2) void conv_kernel(
        const unsigned short* __restrict__ xn2,
        const unsigned short* __restrict__ Wb2,
        float* __restrict__ out) {
    // LDS: P[row 10][px 34][q 3][4 granules of 16B] = 65280 B
    __shared__ __align__(16) unsigned char P[10 * 34 * 3 * 64];

    int bid = blockIdx.x;
    int bx  = bid & 7;          // x tile
    int by  = (bid >> 3) & 31;  // y tile
    int b   = bid >> 8;
    int x0  = bx * 32;
    int y0  = by * 8;
    int tid  = threadIdx.x;
    int lane = tid & 63;
    int w    = tid >> 6;
    int l15  = lane & 15;
    int l4   = lane >> 4;

    f32x4 acc[4][4];
    #pragma unroll
    for (int mt = 0; mt < 4; ++mt)
        #pragma unroll
        for (int nt = 0; nt < 4; ++nt)
            acc[mt][nt] = (f32x4){0.f, 0.f, 0.f, 0.f};

    const bf16x8* wb = (const bf16x8*)Wb2;

    for (int cc = 0; cc < 4; ++cc) {
        __syncthreads();
        // ---- stage powers into LDS: 10 rows x 34 px x 4 granules ----
        const unsigned short* xp = xn2 + (size_t)cc * PLANE + (size_t)b * HWW * 32;
        for (int t = tid; t < 1360; t += 256) {
            int row = t / 136;
            int rem = t - row * 136;
            int px  = rem >> 2;
            int g   = rem & 3;
            int yy  = y0 - 1 + row;
            int xx  = x0 - 1 + px;
            u32x4 u1 = (u32x4){0u, 0u, 0u, 0u};
            if ((unsigned)yy < 256u && (unsigned)xx < 256u)
                u1 = *(const u32x4*)(xp + ((size_t)(yy * 256 + xx)) * 32 + g * 8);
            u32x4 u2, u3;
            #pragma unroll
            for (int k = 0; k < 4; ++k) {
                float f0 = bf16lo_to_f(u1[k]);
                float f1 = bf16hi_to_f(u1[k]);
                float s0 = f0 * f0, s1 = f1 * f1;
                u2[k] = cvt_pk_bf16(s0, s1);
                u3[k] = cvt_pk_bf16(s0 * f0, s1 * f1);
            }
            unsigned char* cell = P + (size_t)(row * 34 + px) * 192 + g * 16;
            *(u32x4*)(cell)       = u1;
            *(u32x4*)(cell + 64)  = u2;
            *(u32x4*)(cell + 128) = u3;
        }
        __syncthreads();

        // ---- 27 taps of MFMA ----
        #pragma unroll
        for (int ky = 0; ky < 3; ++ky) {
            #pragma unroll
            for (int kx = 0; kx < 3; ++kx) {
                #pragma unroll
                for (int q = 0; q < 3; ++q) {
                    bf16x8 a[4];
                    #pragma unroll
                    for (int mt = 0; mt < 4; ++mt) {
                        int rowl = 2 * w + (mt >> 1) + ky;
                        int pxl  = (mt & 1) * 16 + kx + l15;
                        a[mt] = *(const bf16x8*)(P + (size_t)(rowl * 34 + pxl) * 192
                                                 + q * 64 + l4 * 16);
                    }
                    int tq = (ky * 3 + kx) * 3 + q;
                    const bf16x8* wp = wb + (size_t)((tq * 4 + cc) * 4) * 64 + lane;
                    #pragma unroll
                    for (int nt = 0; nt < 4; ++nt) {
                        bf16x8 bv = wp[nt * 64];
                        #pragma unroll
                        for (int mt = 0; mt < 4; ++mt)
                            acc[mt][nt] = __builtin_amdgcn_mfma_f32_16x16x32_bf16(
                                a[mt], bv, acc[mt][nt], 0, 0, 0);
                    }
                }
            }
        }
    }

    // ---- epilogue: fused PixelUnshuffle(2) ----
    #pragma unroll
    for (int mt = 0; mt < 4; ++mt) {
        int y  = y0 + 2 * w + (mt >> 1);
        int s  = (mt >> 1);             // y & 1 (y0, 2w even)
        int y2 = y >> 1;
        int X0 = x0 + (mt & 1) * 16 + l4 * 4;   // even
        int x2 = X0 >> 1;
        #pragma unroll
        for (int nt = 0; nt < 4; ++nt) {
            int oc = nt * 16 + l15;
            #pragma unroll
            for (int rr = 0; rr < 2; ++rr) {
                int ch = oc * 4 + s * 2 + rr;
                size_t off = ((size_t)(b * 256 + ch) * 128 + y2) * 128 + x2;
                f32x2 v;
                v.x = acc[mt][nt][rr];
                v.y = acc[mt][nt][rr + 2];
                *(f32x2*)(out + off) = v;
            }
        }
    }
}

extern "C" void kernel_launch(void* const* d_in, const int* in_sizes, int n_in,
                              void* d_out, int out_size, void* d_ws, size_t ws_size,
                              hipStream_t stream) {
    const float* x     = (const float*)d_in[0];
    const float* gamma = (const float*)d_in[1];
    const float* beta  = (const float*)d_in[2];
    const float* Wc    = (const float*)d_in[3];
    float* out = (float*)d_out;

    const size_t xn_bytes = (size_t)4 * PLANE * 2;               // 134217728
    const size_t wb_bytes = (size_t)27 * 16 * 512 * 2;           // 442368
    if (ws_size < xn_bytes + wb_bytes) return;                   // visible failure
    unsigned short* xn2 = (unsigned short*)d_ws;
    unsigned short* Wb2 = (unsigned short*)((char*)d_ws + xn_bytes);

    hipLaunchKernelGGL(prep_w, dim3(108), dim3(256), 0, stream, Wc, Wb2);
    hipLaunchKernelGGL(ln_kernel, dim3(2048), dim3(256), 0, stream, x, gamma, beta, xn2);
    hipLaunchKernelGGL(conv_kernel, dim3(2048), dim3(256), 0, stream, xn2, Wb2, out);
}

// Round 3
// 296.301 us; speedup vs baseline: 2.2886x; 1.5040x over previous
//
#include <hip/hip_runtime.h>
#include <hip/hip_bf16.h>
#include <stdint.h>

#define BB   8
#define CCH  128
#define HH   256
#define WWD  256
#define OCC  64
#define HWW  (HH*WWD)
#define PLANE (BB*HWW*32)          // elems per 32-ch plane of xn2
#define PITCH 208                  // padded LDS px pitch (bytes); 192 payload + 16 pad

typedef __attribute__((ext_vector_type(8))) short  bf16x8;
typedef __attribute__((ext_vector_type(4))) float  f32x4;
typedef __attribute__((ext_vector_type(4))) unsigned int u32x4;
typedef __attribute__((ext_vector_type(2))) float  f32x2;

static __device__ __forceinline__ unsigned cvt_pk_bf16(float lo, float hi) {
    unsigned r;
    asm("v_cvt_pk_bf16_f32 %0, %1, %2" : "=v"(r) : "v"(lo), "v"(hi));
    return r;
}
static __device__ __forceinline__ float bf16lo_to_f(unsigned u) {
    union { unsigned u; float f; } c; c.u = u << 16; return c.f;
}
static __device__ __forceinline__ float bf16hi_to_f(unsigned u) {
    union { unsigned u; float f; } c; c.u = u & 0xffff0000u; return c.f;
}

// Repack Wc (OC, Q*C, 3, 3) fp32 -> Wb2: per-fragment lane-order bf16.
// frag = ((tap*3+q)*4+cc)*4+nt ; within frag: lane*8 contiguous bf16,
// lane -> (oc = nt*16 + (lane&15), k = cc*32 + (lane>>4)*8 + j).
__global__ void prep_w(const float* __restrict__ Wc, unsigned short* __restrict__ Wb2) {
    int task = blockIdx.x * 256 + threadIdx.x;    // 27648 tasks, one bf16x8 each
    int lane = task & 63;
    int frag = task >> 6;
    int nt   = frag & 3;
    int cc   = (frag >> 2) & 3;
    int tq   = frag >> 4;                         // tap*3+q, 0..26
    int q    = tq % 3;
    int tap  = tq / 3;
    int oc   = nt * 16 + (lane & 15);
    int kb   = cc * 32 + (lane >> 4) * 8;
    u32x4 o;
    #pragma unroll
    for (int k = 0; k < 4; ++k) {
        float v0 = Wc[(size_t)(oc * 384 + q * 128 + kb + 2 * k) * 9 + tap];
        float v1 = Wc[(size_t)(oc * 384 + q * 128 + kb + 2 * k + 1) * 9 + tap];
        o[k] = cvt_pk_bf16(v0, v1);
    }
    *(u32x4*)(Wb2 + (size_t)task * 8) = o;
}

// Per-pixel LayerNorm over C=128; write xn2 as 4 planes [cc][b][y][x][32ch] bf16
__global__ __launch_bounds__(256) void ln_kernel(
        const float* __restrict__ x, const float* __restrict__ gamma,
        const float* __restrict__ beta, unsigned short* __restrict__ xn2) {
    int p  = blockIdx.x * 256 + threadIdx.x;      // global pixel
    int b  = p >> 16;
    int hw = p & 65535;
    const float* xb = x + (size_t)b * CCH * HWW + hw;
    unsigned buf[64];
    float sum = 0.f, sumsq = 0.f;
    #pragma unroll
    for (int cp = 0; cp < 64; ++cp) {
        float v0 = xb[(size_t)(2 * cp) * HWW];
        float v1 = xb[(size_t)(2 * cp + 1) * HWW];
        sum   += v0 + v1;
        sumsq += v0 * v0 + v1 * v1;
        buf[cp] = cvt_pk_bf16(v0, v1);
    }
    float mu  = sum * (1.f / 128.f);
    float var = sumsq * (1.f / 128.f) - mu * mu;
    float rs  = rsqrtf(var + 1e-5f);
    size_t pix = (size_t)p * 32;
    #pragma unroll
    for (int g = 0; g < 16; ++g) {
        u32x4 o;
        #pragma unroll
        for (int k = 0; k < 4; ++k) {
            int cp = g * 4 + k;
            float f0 = bf16lo_to_f(buf[cp]);
            float f1 = bf16hi_to_f(buf[cp]);
            int c0 = cp * 2, c1 = cp * 2 + 1;
            float y0 = fmaf((f0 - mu) * rs, gamma[c0], beta[c0]);
            float y1 = fmaf((f1 - mu) * rs, gamma[c1], beta[c1]);
            o[k] = cvt_pk_bf16(y0, y1);
        }
        *(u32x4*)(xn2 + (size_t)(g >> 2) * PLANE + pix + (g & 3) * 8) = o;
    }
}

// Implicit-GEMM conv. Block = 8 rows x 32 px x 64 oc; 4 waves (each 2 rows x 32 px).
// Pipelined: chunk cc+1 global loads fly under chunk cc's 27 taps of MFMA (T14);
// A (LDS) and B (global) fragments double-buffered one tap ahead.
__global__ __launch_bounds__(256, 2) void conv_kernel(
        const unsigned short* __restrict__ xn2,
        const unsigned short* __restrict__ Wb2,
        float* __restrict__ out) {
    // LDS: P[row 10][px 34][PITCH bytes: q*64 + granule*16, 16B pad] = 70720 B
    __shared__ __align__(16) unsigned char P[10 * 34 * PITCH];

    int bid = blockIdx.x;
    int bx  = bid & 7;          // x tile
    int by  = (bid >> 3) & 31;  // y tile
    int b   = bid >> 8;
    int x0  = bx * 32;
    int y0  = by * 8;
    int tid  = threadIdx.x;
    int lane = tid & 63;
    int w    = tid >> 6;
    int l15  = lane & 15;
    int l4   = lane >> 4;

    f32x4 acc[4][4];
    #pragma unroll
    for (int mt = 0; mt < 4; ++mt)
        #pragma unroll
        for (int nt = 0; nt < 4; ++nt)
            acc[mt][nt] = (f32x4){0.f, 0.f, 0.f, 0.f};

    // ---- staging geometry (cc-invariant) ----
    int offg[6];                 // elem offset within a plane (per batch)
    int woff[6];                 // LDS byte offset
    bool vldf[6], wrf[6];
    #pragma unroll
    for (int it = 0; it < 6; ++it) {
        int item = tid + it * 256;
        bool ok  = item < 1360;
        int ii   = ok ? item : 0;
        int row  = ii / 136;
        int rem  = ii - row * 136;
        int px   = rem >> 2;
        int g    = rem & 3;
        int yy   = y0 - 1 + row;
        int xx   = x0 - 1 + px;
        bool inb = ok && (unsigned)yy < 256u && (unsigned)xx < 256u;
        offg[it] = (yy * 256 + xx) * 32 + g * 8;
        woff[it] = (row * 34 + px) * PITCH + g * 16;
        vldf[it] = inb;
        wrf[it]  = ok;
    }

    const unsigned short* xpb = xn2 + (size_t)b * HWW * 32;
    const bf16x8* wlane = (const bf16x8*)Wb2 + lane;
    const unsigned char* pa = P + (2 * w * 34 + l15) * PITCH + l4 * 16;

    // ---- prologue: issue chunk-0 staging loads ----
    u32x4 rs[6];
    #pragma unroll
    for (int it = 0; it < 6; ++it) {
        u32x4 v = (u32x4){0u, 0u, 0u, 0u};
        if (vldf[it]) v = *(const u32x4*)(xpb + offg[it]);
        rs[it] = v;
    }

    #pragma unroll 1
    for (int cc = 0; cc < 4; ++cc) {
        if (cc > 0) __syncthreads();          // all waves done reading prev chunk
        // ---- write powers to LDS from staged regs ----
        #pragma unroll
        for (int it = 0; it < 6; ++it) {
            if (!wrf[it]) continue;
            u32x4 u1 = rs[it];
            u32x4 u2, u3;
            #pragma unroll
            for (int k = 0; k < 4; ++k) {
                float f0 = bf16lo_to_f(u1[k]);
                float f1 = bf16hi_to_f(u1[k]);
                float s0 = f0 * f0, s1 = f1 * f1;
                u2[k] = cvt_pk_bf16(s0, s1);
                u3[k] = cvt_pk_bf16(s0 * f0, s1 * f1);
            }
            unsigned char* cell = P + woff[it];
            *(u32x4*)(cell)       = u1;
            *(u32x4*)(cell + 64)  = u2;
            *(u32x4*)(cell + 128) = u3;
        }
        __syncthreads();

        // ---- issue chunk cc+1 staging loads (fly under the MFMAs below) ----
        if (cc < 3) {
            const unsigned short* xpn = xpb + (size_t)(cc + 1) * PLANE;
            #pragma unroll
            for (int it = 0; it < 6; ++it) {
                u32x4 v = (u32x4){0u, 0u, 0u, 0u};
                if (vldf[it]) v = *(const u32x4*)(xpn + offg[it]);
                rs[it] = v;
            }
        }

        // ---- 27 taps, software-pipelined A/B fragment prefetch ----
        const bf16x8* wcc = wlane + cc * 4 * 64;
        bf16x8 av[2][4], bvv[2][4];
        #pragma unroll
        for (int mt = 0; mt < 4; ++mt)
            av[0][mt] = *(const bf16x8*)(pa + ((mt >> 1)) * (34 * PITCH)
                                            + ((mt & 1) * 16) * PITCH);
        #pragma unroll
        for (int nt = 0; nt < 4; ++nt)
            bvv[0][nt] = wcc[nt * 64];

        #pragma unroll
        for (int tq = 0; tq < 27; ++tq) {
            int cur = tq & 1, nxt = cur ^ 1;
            if (tq < 26) {
                int t2 = tq + 1;
                int ky = t2 / 9, kx = (t2 / 3) % 3, q = t2 % 3;
                #pragma unroll
                for (int mt = 0; mt < 4; ++mt)
                    av[nxt][mt] = *(const bf16x8*)(pa
                        + ((mt >> 1) + ky) * (34 * PITCH)
                        + ((mt & 1) * 16 + kx) * PITCH + q * 64);
                #pragma unroll
                for (int nt = 0; nt < 4; ++nt)
                    bvv[nxt][nt] = wcc[(t2 * 16 + nt) * 64];
            }
            __builtin_amdgcn_s_setprio(1);
            #pragma unroll
            for (int nt = 0; nt < 4; ++nt)
                #pragma unroll
                for (int mt = 0; mt < 4; ++mt)
                    acc[mt][nt] = __builtin_amdgcn_mfma_f32_16x16x32_bf16(
                        av[cur][mt], bvv[cur][nt], acc[mt][nt], 0, 0, 0);
            __builtin_amdgcn_s_setprio(0);
        }
    }

    // ---- epilogue: fused PixelUnshuffle(2) ----
    #pragma unroll
    for (int mt = 0; mt < 4; ++mt) {
        int y  = y0 + 2 * w + (mt >> 1);
        int s  = (mt >> 1);             // y & 1 (y0, 2w even)
        int y2 = y >> 1;
        int X0 = x0 + (mt & 1) * 16 + l4 * 4;   // even
        int x2 = X0 >> 1;
        #pragma unroll
        for (int nt = 0; nt < 4; ++nt) {
            int oc = nt * 16 + l15;
            #pragma unroll
            for (int rr = 0; rr < 2; ++rr) {
                int ch = oc * 4 + s * 2 + rr;
                size_t off = ((size_t)(b * 256 + ch) * 128 + y2) * 128 + x2;
                f32x2 v;
                v.x = acc[mt][nt][rr];
                v.y = acc[mt][nt][rr + 2];
                *(f32x2*)(out + off) = v;
            }
        }
    }
}

extern "C" void kernel_launch(void* const* d_in, const int* in_sizes, int n_in,
                              void* d_out, int out_size, void* d_ws, size_t ws_size,
                              hipStream_t stream) {
    const float* x     = (const float*)d_in[0];
    const float* gamma = (const float*)d_in[1];
    const float* beta  = (const float*)d_in[2];
    const float* Wc    = (const float*)d_in[3];
    float* out = (float*)d_out;

    const size_t xn_bytes = (size_t)4 * PLANE * 2;               // 134217728
    const size_t wb_bytes = (size_t)27 * 16 * 512 * 2;           // 442368
    if (ws_size < xn_bytes + wb_bytes) return;                   // visible failure
    unsigned short* xn2 = (unsigned short*)d_ws;
    unsigned short* Wb2 = (unsigned short*)((char*)d_ws + xn_bytes);

    hipLaunchKernelGGL(prep_w, dim3(108), dim3(256), 0, stream, Wc, Wb2);
    hipLaunchKernelGGL(ln_kernel, dim3(2048), dim3(256), 0, stream, x, gamma, beta, xn2);
    hipLaunchKernelGGL(conv_kernel, dim3(2048), dim3(256), 0, stream, xn2, Wb2, out);
}